// Round 5
// baseline (115.422 us; speedup 1.0000x reference)
//
#include <hip/hip_runtime.h>
#include <math.h>

typedef short bf16x8 __attribute__((ext_vector_type(8)));
typedef float f32x4 __attribute__((ext_vector_type(4)));
typedef unsigned short u16;

#define NT 256
#define C1c 1e-4f
#define C2c 9e-4f

// f32 -> bf16 round-to-nearest-even (non-negative, finite inputs)
__device__ inline u16 f2bf(float f) {
    unsigned u = __float_as_uint(f);
    return (u16)((u + 0x7FFFu + ((u >> 16) & 1u)) >> 16);
}
__device__ inline float bf2f(u16 h) { return __uint_as_float((unsigned)h << 16); }

// rotation swizzle: bijective within an 80-column row; element-wise valid.
// 4/8-aligned blocks never straddle the wrap since 80 % 8 == 0.
__device__ inline int rot80(int c, int row) {
    int cc = c + 8 * (row & 7);
    return (cc >= 80) ? cc - 80 : cc;
}

// BISECT round: stage-0 (bf16 LDS) + T layout + pass-2 MFMA kept identical to
// round 4; pass-1 MFMA replaced by a VALU horizontal conv writing the same T.
//   PASS  -> bug was in pass-1 MFMA path (products/wB/C-store).
//   FAIL  -> bug is in {stage-0, T layout, pass-2 MFMA (weights-as-A)}.
template <bool ATOMIC>
__global__ __launch_bounds__(NT, 2) void ssim_bisect(
    const float* __restrict__ img1, const float* __restrict__ img2,
    const float* __restrict__ window, float* __restrict__ partials)
{
    __shared__ alignas(16) u16 in1[80 * 80];   // [ry][c], c = gx-(x0-8), rot-swizzled
    __shared__ alignas(16) u16 in2[80 * 80];
    __shared__ alignas(16) u16 T[5][64 * 80];  // [field][x][yhalo], rot-swizzled
    __shared__ u16 wtab[64];                   // bf16 g at slots 20..30, zeros else
    __shared__ float wred[4];

    const int tid = threadIdx.x;
    const int x0 = blockIdx.x * 64;
    const int y0 = blockIdx.y * 64;
    const float* p1 = img1 + (size_t)blockIdx.z * (512 * 512);
    const float* p2 = img2 + (size_t)blockIdx.z * (512 * 512);

    // ---- weight table (for pass-2 wA): zeros + error-feedback bf16 quant ----
    if (tid < 64 && (tid < 20 || tid > 30)) wtab[tid] = 0;
    if (tid == 0) {
        float inv = 1.0f / sqrtf(window[60]);      // w2[5][5] = g5^2
        float carry = 0.f;
        for (int k = 0; k < 11; ++k) {
            float gk = window[55 + k] * inv + carry;
            u16 q = f2bf(gk);
            carry = gk - bf2f(q);
            wtab[20 + k] = q;
        }
    }

    // per-thread f32 gaussian for the VALU pass
    float gf[11];
    {
        float inv = rsqrtf(window[60]);
        #pragma unroll
        for (int t = 0; t < 11; ++t) gf[t] = window[55 + t] * inv;
    }

    // ---- stage 0: img1/img2 tiles -> bf16 LDS (rows 74..79 zeroed) ----
    for (int l = tid; l < 3200; l += NT) {
        int chunk = l % 20;            // 4-float chunk in row
        int rest = l / 20;
        int ry = rest % 80;            // y-halo row (74 real + 6 pad)
        int img = rest / 80;
        int gy = y0 - 5 + ry;
        int gxb = x0 - 8 + chunk * 4;  // 16B-aligned global col base
        float4 v = make_float4(0.f, 0.f, 0.f, 0.f);
        if (ry < 74 && (unsigned)gy < 512u && gxb >= 0 && gxb <= 508) {
            const float* p = img ? p2 : p1;
            v = *(const float4*)(p + gy * 512 + gxb);
        }
        unsigned lo, hi;
        asm("v_cvt_pk_bf16_f32 %0, %1, %2" : "=v"(lo) : "v"(v.x), "v"(v.y));
        asm("v_cvt_pk_bf16_f32 %0, %1, %2" : "=v"(hi) : "v"(v.z), "v"(v.w));
        int e = ry * 80 + rot80(chunk * 4, ry);
        u16* dst = img ? in2 : in1;
        *(uint2*)&dst[e] = make_uint2(lo, hi);
    }
    __syncthreads();

    const int lane = tid & 63;
    const int lrow = lane & 15;
    const int lgrp = lane >> 4;
    const int wid = tid >> 6;

    // ---- pass 1 (VALU): horizontal conv of 5 fields, write T[x][ry] ----
    {
        int x   = tid & 63;
        int ryq = tid >> 6;            // 4 quads of 20 rows
        for (int rr = 0; rr < 5; ++rr) {
            int base4 = ryq * 20 + rr * 4;
            u16 pk[5][4];
            #pragma unroll
            for (int i = 0; i < 4; ++i) {
                int ry = base4 + i;
                float h0 = 0.f, h1 = 0.f, h2 = 0.f, h3 = 0.f, h4 = 0.f;
                #pragma unroll
                for (int t = 0; t < 11; ++t) {
                    int c = x + 3 + t;
                    int e = ry * 80 + rot80(c, ry);
                    float a = bf2f(in1[e]);
                    float b = bf2f(in2[e]);
                    float gt = gf[t];
                    h0 += gt * a;
                    h1 += gt * b;
                    h2 += gt * a * a;
                    h3 += gt * b * b;
                    h4 += gt * a * b;
                }
                pk[0][i] = f2bf(h0); pk[1][i] = f2bf(h1); pk[2][i] = f2bf(h2);
                pk[3][i] = f2bf(h3); pk[4][i] = f2bf(h4);
            }
            int te = x * 80 + rot80(base4, x);
            #pragma unroll
            for (int f = 0; f < 5; ++f) {
                uint2 wv;
                wv.x = (unsigned)pk[f][0] | ((unsigned)pk[f][1] << 16);
                wv.y = (unsigned)pk[f][2] | ((unsigned)pk[f][3] << 16);
                *(uint2*)&T[f][te] = wv;
            }
        }
    }
    __syncthreads();

    // ---- pass 2 (MFMA, unchanged from round 4): vertical conv + SSIM ----
    bf16x8 wA;
    #pragma unroll
    for (int j = 0; j < 8; ++j) {
        int k = lgrp * 8 + j;
        wA[j] = (short)wtab[20 + k - lrow];      // W2[i][k] = g[k - i]
    }
    f32x4 z4 = {0.f, 0.f, 0.f, 0.f};

    float lsum = 0.f;
    for (int p = wid; p < 16; p += 4) {
        int m2 = p >> 2, n2 = p & 3;
        int tx = 16 * n2 + lrow;
        int te = tx * 80 + rot80(16 * m2 + 8 * lgrp, tx);
        f32x4 cf[5];
        #pragma unroll
        for (int f = 0; f < 5; ++f) {
            uint4 q = *(const uint4*)&T[f][te];
            cf[f] = __builtin_amdgcn_mfma_f32_16x16x32_bf16(wA, __builtin_bit_cast(bf16x8, q), z4, 0, 0, 0);
        }
        #pragma unroll
        for (int r = 0; r < 4; ++r) {
            float mu1 = cf[0][r], mu2 = cf[1][r];
            float m11 = mu1 * mu1, m22 = mu2 * mu2, m12 = mu1 * mu2;
            float s1 = cf[2][r] - m11;
            float s2 = cf[3][r] - m22;
            float s12 = cf[4][r] - m12;
            float num = (2.f * m12 + C1c) * (2.f * s12 + C2c);
            float den = (m11 + m22 + C1c) * (s1 + s2 + C2c);
            float v = num * __builtin_amdgcn_rcpf(den);
            lsum += fminf(fmaxf(v, 0.f), 1.f);
        }
    }

    // ---- block reduce ----
    #pragma unroll
    for (int off = 32; off > 0; off >>= 1) lsum += __shfl_down(lsum, off);
    if ((tid & 63) == 0) wred[wid] = lsum;
    __syncthreads();
    if (tid == 0) {
        float bsum = wred[0] + wred[1] + wred[2] + wred[3];
        int bid = (blockIdx.z * gridDim.y + blockIdx.y) * gridDim.x + blockIdx.x;
        if (ATOMIC) atomicAdd(&partials[0], bsum);
        else        partials[bid] = bsum;
    }
}

__global__ void ssim_finalize(const float* __restrict__ partials, int n,
                              float* __restrict__ out, float inv_npx)
{
    __shared__ float w[4];
    float s = 0.f;
    for (int i = threadIdx.x; i < n; i += 256) s += partials[i];
    #pragma unroll
    for (int off = 32; off > 0; off >>= 1) s += __shfl_down(s, off);
    if ((threadIdx.x & 63) == 0) w[threadIdx.x >> 6] = s;
    __syncthreads();
    if (threadIdx.x == 0) {
        float total = w[0] + w[1] + w[2] + w[3];
        float loss = 1.0f - total * inv_npx;
        out[0] = fmaxf(loss, 0.0f);
    }
}

extern "C" void kernel_launch(void* const* d_in, const int* in_sizes, int n_in,
                              void* d_out, int out_size, void* d_ws, size_t ws_size,
                              hipStream_t stream) {
    const float* img1   = (const float*)d_in[0];
    const float* img2   = (const float*)d_in[1];
    const float* window = (const float*)d_in[2];
    float* out      = (float*)d_out;
    float* partials = (float*)d_ws;

    int planes = in_sizes[0] >> 18;          // 48
    dim3 grid(512 / 64, 512 / 64, planes);   // 8 x 8 x 48 = 3072 blocks
    int npart = grid.x * grid.y * grid.z;
    float inv_npx = 1.0f / (float)in_sizes[0];

    if (ws_size >= (size_t)npart * sizeof(float)) {
        ssim_bisect<false><<<grid, NT, 0, stream>>>(img1, img2, window, partials);
        ssim_finalize<<<1, 256, 0, stream>>>(partials, npart, out, inv_npx);
    } else {
        hipMemsetAsync(d_ws, 0, sizeof(float), stream);
        ssim_bisect<true><<<grid, NT, 0, stream>>>(img1, img2, window, partials);
        ssim_finalize<<<1, 256, 0, stream>>>(partials, 1, out, inv_npx);
    }
}

// Round 7
// 68.355 us; speedup vs baseline: 1.6886x; 1.6886x over previous
//
#include <hip/hip_runtime.h>
#include <math.h>

typedef float f32x2 __attribute__((ext_vector_type(2)));

#define TW 64
#define TH 32
#define XH 74        // TW + 10 halo columns
#define VCW 76       // padded row stride
#define NT 256
#define SSIM_C1 1e-4f
#define SSIM_C2 9e-4f

// Pure-VALU separable SSIM (r2 structure) with packed-f32 pair math:
// output pairs (2i2, 2i2+1) accumulate via one f32x2 FMA against
// gp[t] = (g[t], g[t-1]) -> v_pk_fma_f32.
template <bool ATOMIC>
__global__ __launch_bounds__(NT, 3) void ssim_pk(
    const float* __restrict__ img1, const float* __restrict__ img2,
    const float* __restrict__ window, float* __restrict__ partials)
{
    __shared__ float vc[5][TH][VCW];   // 5*32*76*4 = 48640 B
    __shared__ float wred[4];

    const int tid = threadIdx.x;
    const int x0 = blockIdx.x * TW;
    const int y0 = blockIdx.y * TH;
    const float* p1 = img1 + (size_t)blockIdx.z * (512 * 512);
    const float* p2 = img2 + (size_t)blockIdx.z * (512 * 512);

    // 1D gaussian from window row 5 (w2[5][j] = g5*g[j], w2[5][5] = g5^2)
    float g[11];
    {
        float r5 = rsqrtf(window[60]);
        #pragma unroll
        for (int j = 0; j < 11; ++j) g[j] = window[55 + j] * r5;
    }
    // pair table: gp[t] = (g[t], g[t-1]), zero-padded at the ends
    f32x2 gp[12];
    gp[0] = (f32x2){g[0], 0.f};
    #pragma unroll
    for (int t = 1; t < 11; ++t) gp[t] = (f32x2){g[t], g[t - 1]};
    gp[11] = (f32x2){0.f, g[10]};

    // ---- pass 1: vertical conv (74 cols x 4 y-octets = 296 tasks) ----
    for (int l = tid; l < XH * (TH / 8); l += NT) {
        int xh = l % XH;
        int yq = l / XH;
        int gx = x0 - 5 + xh;
        int yb = y0 + yq * 8;
        bool xok = (unsigned)gx < 512u;

        float ra[18], rb[18];
        #pragma unroll
        for (int j = 0; j < 18; ++j) {
            int gy = yb - 5 + j;
            float a = 0.f, b = 0.f;
            if (xok && (unsigned)gy < 512u) {
                int idx = gy * 512 + gx;
                a = p1[idx];
                b = p2[idx];
            }
            ra[j] = a; rb[j] = b;
        }

        f32x2 acc[5][4];
        #pragma unroll
        for (int f = 0; f < 5; ++f)
            #pragma unroll
            for (int i2 = 0; i2 < 4; ++i2) acc[f][i2] = (f32x2){0.f, 0.f};

        #pragma unroll
        for (int j = 0; j < 18; ++j) {
            float a = ra[j], b = rb[j];
            float aa = a * a, bb = b * b, ab = a * b;
            #pragma unroll
            for (int i2 = 0; i2 < 4; ++i2) {
                int t = j - 2 * i2;
                if (t >= 0 && t < 12) {
                    f32x2 w = gp[t];
                    acc[0][i2] += w * a;
                    acc[1][i2] += w * b;
                    acc[2][i2] += w * aa;
                    acc[3][i2] += w * bb;
                    acc[4][i2] += w * ab;
                }
            }
        }
        int yb8 = yq * 8;
        #pragma unroll
        for (int f = 0; f < 5; ++f)
            #pragma unroll
            for (int i2 = 0; i2 < 4; ++i2) {
                vc[f][yb8 + 2 * i2 + 0][xh] = acc[f][i2].x;
                vc[f][yb8 + 2 * i2 + 1][xh] = acc[f][i2].y;
            }
    }
    __syncthreads();

    // ---- pass 2: horizontal conv + SSIM (8 x-octets x 32 rows) ----
    float lsum = 0.f;
    {
        int x8 = (tid & 7) * 8;   // output x octet base (local)
        int yl = tid >> 3;        // output row (local), 0..31
        f32x2 m2[5][4];
        #pragma unroll
        for (int f = 0; f < 5; ++f) {
            const float* row = &vc[f][yl][x8];
            float4 q0 = *(const float4*)(row);
            float4 q1 = *(const float4*)(row + 4);
            float4 q2 = *(const float4*)(row + 8);
            float4 q3 = *(const float4*)(row + 12);
            float4 q4 = *(const float4*)(row + 16);
            float v[20] = {q0.x,q0.y,q0.z,q0.w, q1.x,q1.y,q1.z,q1.w,
                           q2.x,q2.y,q2.z,q2.w, q3.x,q3.y,q3.z,q3.w,
                           q4.x,q4.y,q4.z,q4.w};
            f32x2 acc[4];
            #pragma unroll
            for (int i2 = 0; i2 < 4; ++i2) acc[i2] = (f32x2){0.f, 0.f};
            #pragma unroll
            for (int j = 0; j < 18; ++j) {
                float s = v[j];
                #pragma unroll
                for (int i2 = 0; i2 < 4; ++i2) {
                    int t = j - 2 * i2;
                    if (t >= 0 && t < 12) acc[i2] += gp[t] * s;
                }
            }
            #pragma unroll
            for (int i2 = 0; i2 < 4; ++i2) m2[f][i2] = acc[i2];
        }
        #pragma unroll
        for (int i2 = 0; i2 < 4; ++i2) {
            f32x2 mu1 = m2[0][i2], mu2 = m2[1][i2];
            f32x2 m11 = mu1 * mu1, m22 = mu2 * mu2, m12 = mu1 * mu2;
            f32x2 s1 = m2[2][i2] - m11;
            f32x2 s2 = m2[3][i2] - m22;
            f32x2 s12 = m2[4][i2] - m12;
            f32x2 num = (2.f * m12 + SSIM_C1) * (2.f * s12 + SSIM_C2);
            f32x2 den = (m11 + m22 + SSIM_C1) * (s1 + s2 + SSIM_C2);
            float v0 = num.x * __builtin_amdgcn_rcpf(den.x);
            float v1 = num.y * __builtin_amdgcn_rcpf(den.y);
            lsum += fminf(fmaxf(v0, 0.f), 1.f);
            lsum += fminf(fmaxf(v1, 0.f), 1.f);
        }
    }

    // ---- block reduce ----
    #pragma unroll
    for (int off = 32; off > 0; off >>= 1) lsum += __shfl_down(lsum, off);
    if ((tid & 63) == 0) wred[tid >> 6] = lsum;
    __syncthreads();
    if (tid == 0) {
        float bsum = wred[0] + wred[1] + wred[2] + wred[3];
        int bid = (blockIdx.z * gridDim.y + blockIdx.y) * gridDim.x + blockIdx.x;
        if (ATOMIC) atomicAdd(&partials[0], bsum);
        else        partials[bid] = bsum;
    }
}

__global__ void ssim_finalize(const float* __restrict__ partials, int n,
                              float* __restrict__ out, float inv_npx)
{
    __shared__ float w[4];
    float s = 0.f;
    for (int i = threadIdx.x; i < n; i += 256) s += partials[i];
    #pragma unroll
    for (int off = 32; off > 0; off >>= 1) s += __shfl_down(s, off);
    if ((threadIdx.x & 63) == 0) w[threadIdx.x >> 6] = s;
    __syncthreads();
    if (threadIdx.x == 0) {
        float total = w[0] + w[1] + w[2] + w[3];
        float loss = 1.0f - total * inv_npx;
        out[0] = fmaxf(loss, 0.0f);
    }
}

extern "C" void kernel_launch(void* const* d_in, const int* in_sizes, int n_in,
                              void* d_out, int out_size, void* d_ws, size_t ws_size,
                              hipStream_t stream) {
    const float* img1   = (const float*)d_in[0];
    const float* img2   = (const float*)d_in[1];
    const float* window = (const float*)d_in[2];
    float* out      = (float*)d_out;
    float* partials = (float*)d_ws;

    int planes = in_sizes[0] >> 18;          // 48
    dim3 grid(512 / TW, 512 / TH, planes);   // 8 x 16 x 48 = 6144 blocks
    int npart = grid.x * grid.y * grid.z;
    float inv_npx = 1.0f / (float)in_sizes[0];

    if (ws_size >= (size_t)npart * sizeof(float)) {
        ssim_pk<false><<<grid, NT, 0, stream>>>(img1, img2, window, partials);
        ssim_finalize<<<1, 256, 0, stream>>>(partials, npart, out, inv_npx);
    } else {
        hipMemsetAsync(d_ws, 0, sizeof(float), stream);
        ssim_pk<true><<<grid, NT, 0, stream>>>(img1, img2, window, partials);
        ssim_finalize<<<1, 256, 0, stream>>>(partials, 1, out, inv_npx);
    }
}